// Round 2
// baseline (586.450 us; speedup 1.0000x reference)
//
#include <hip/hip_runtime.h>
#include <hip/hip_bf16.h>
#include <cstdint>
#include <cstddef>

typedef unsigned short u16;
typedef __bf16 bf16x8 __attribute__((ext_vector_type(8)));
typedef float f32x4 __attribute__((ext_vector_type(4)));
typedef unsigned short u16x4 __attribute__((ext_vector_type(4)));

#define AS1(p) ((__attribute__((address_space(1))) void*)(p))
#define AS3(p) ((__attribute__((address_space(3))) void*)(p))

__device__ __forceinline__ float bf2f(u16 u) {
  unsigned v = ((unsigned)u) << 16; float f; __builtin_memcpy(&f, &v, 4); return f;
}
__device__ __forceinline__ u16 f2bf(float f) {
  unsigned u; __builtin_memcpy(&u, &f, 4);
  u += 0x7FFFu + ((u >> 16) & 1u);   // RNE
  return (u16)(u >> 16);
}

// ---------------- fp32 -> bf16 convert (plain) ----------------
__global__ __launch_bounds__(256) void convert_kernel(const float* __restrict__ src,
                                                      u16* __restrict__ dst, int n4) {
  int i = blockIdx.x * blockDim.x + threadIdx.x;
  int stride = gridDim.x * blockDim.x;
  for (; i < n4; i += stride) {
    float4 v = ((const float4*)src)[i];
    u16x4 o;
    o.x = f2bf(v.x); o.y = f2bf(v.y); o.z = f2bf(v.z); o.w = f2bf(v.w);
    ((u16x4*)dst)[i] = o;
  }
}

// ---------------- fp32 -> bf16 hi + bf16 lo (2-term split) ----------------
__global__ __launch_bounds__(256) void convert_split_kernel(const float* __restrict__ src,
                                                            u16* __restrict__ hi,
                                                            u16* __restrict__ lo, int n4) {
  int i = blockIdx.x * blockDim.x + threadIdx.x;
  int stride = gridDim.x * blockDim.x;
  for (; i < n4; i += stride) {
    float4 v = ((const float4*)src)[i];
    u16x4 oh, ol;
    oh.x = f2bf(v.x); ol.x = f2bf(v.x - bf2f(oh.x));
    oh.y = f2bf(v.y); ol.y = f2bf(v.y - bf2f(oh.y));
    oh.z = f2bf(v.z); ol.z = f2bf(v.z - bf2f(oh.z));
    oh.w = f2bf(v.w); ol.w = f2bf(v.w - bf2f(oh.w));
    ((u16x4*)hi)[i] = oh;
    ((u16x4*)lo)[i] = ol;
  }
}

// ---------------- m97-style GEMM: C[M,N] = A[M,K] * B[N,K]^T (single bf16) ----------------
template<bool OUT_BF16, bool HAS_BIAS>
__global__ __launch_bounds__(256) void gemm_bt(const u16* __restrict__ A,
                                               const u16* __restrict__ B,
                                               void* __restrict__ Cv,
                                               const float* __restrict__ bias,
                                               int M, int N, int K) {
  __shared__ __align__(16) u16 lA[128 * 32];
  __shared__ __align__(16) u16 lB[128 * 32];
  const int tid  = threadIdx.x;
  const int lane = tid & 63;
  const int wave = tid >> 6;
  const int rowTile = blockIdx.x * 128;
  const int colTile = blockIdx.y * 128;
  const int wr = (wave >> 1) * 64;
  const int wc = (wave & 1) * 64;

  f32x4 acc[4][4] = {};
  const int m  = lane & 15;
  const int ko = (lane >> 4) * 8;

  for (int kt = 0; kt < K; kt += 32) {
#pragma unroll
    for (int i = 0; i < 2; ++i) {
      int idx = i * 256 + tid;
      int row = idx >> 2;
      int kc  = (idx & 3) * 8;
      int ldsOff = (i * 256 + (tid & 192)) * 16;   // wave-uniform base; HW adds lane*16
      __builtin_amdgcn_global_load_lds(AS1(A + (size_t)(rowTile + row) * K + kt + kc),
                                       AS3((char*)lA + ldsOff), 16, 0, 0);
      __builtin_amdgcn_global_load_lds(AS1(B + (size_t)(colTile + row) * K + kt + kc),
                                       AS3((char*)lB + ldsOff), 16, 0, 0);
    }
    __syncthreads();
    bf16x8 af[4], bfr[4];
#pragma unroll
    for (int rb = 0; rb < 4; ++rb)
      af[rb] = *(const bf16x8*)(lA + (wr + rb * 16 + m) * 32 + ko);
#pragma unroll
    for (int cb = 0; cb < 4; ++cb)
      bfr[cb] = *(const bf16x8*)(lB + (wc + cb * 16 + m) * 32 + ko);
#pragma unroll
    for (int rb = 0; rb < 4; ++rb)
#pragma unroll
      for (int cb = 0; cb < 4; ++cb)
        acc[rb][cb] = __builtin_amdgcn_mfma_f32_16x16x32_bf16(af[rb], bfr[cb], acc[rb][cb], 0, 0, 0);
    __syncthreads();
  }

  const int crow0 = rowTile + wr + (lane >> 4) * 4;
  const int ccol0 = colTile + wc + (lane & 15);
#pragma unroll
  for (int rb = 0; rb < 4; ++rb) {
#pragma unroll
    for (int cb = 0; cb < 4; ++cb) {
      int col = ccol0 + cb * 16;
      float bv = HAS_BIAS ? bias[col] : 0.f;
#pragma unroll
      for (int r = 0; r < 4; ++r) {
        int row = crow0 + rb * 16 + r;
        float v = acc[rb][cb][r] + bv;
        if (OUT_BF16) ((u16*)Cv)[(size_t)row * N + col] = f2bf(v);
        else          ((float*)Cv)[(size_t)row * N + col] = v;
      }
    }
  }
}

// ---------------- split-bf16 GEMM: C[M,N] fp32 = (Ah+Al)(Bh+Bl)^T, drop lo*lo ----------------
__global__ __launch_bounds__(256) void gemm_qk_split(const u16* __restrict__ Ah,
                                                     const u16* __restrict__ Al,
                                                     const u16* __restrict__ Bh,
                                                     const u16* __restrict__ Bl,
                                                     float* __restrict__ C,
                                                     int M, int N, int K) {
  __shared__ __align__(16) u16 lAh[128 * 32];
  __shared__ __align__(16) u16 lAl[128 * 32];
  __shared__ __align__(16) u16 lBh[128 * 32];
  __shared__ __align__(16) u16 lBl[128 * 32];
  const int tid  = threadIdx.x;
  const int lane = tid & 63;
  const int wave = tid >> 6;
  const int rowTile = blockIdx.x * 128;
  const int colTile = blockIdx.y * 128;
  const int wr = (wave >> 1) * 64;
  const int wc = (wave & 1) * 64;

  f32x4 acc[4][4] = {};
  const int m  = lane & 15;
  const int ko = (lane >> 4) * 8;

  for (int kt = 0; kt < K; kt += 32) {
#pragma unroll
    for (int i = 0; i < 2; ++i) {
      int idx = i * 256 + tid;
      int row = idx >> 2;
      int kc  = (idx & 3) * 8;
      int ldsOff = (i * 256 + (tid & 192)) * 16;
      size_t aoff = (size_t)(rowTile + row) * K + kt + kc;
      size_t boff = (size_t)(colTile + row) * K + kt + kc;
      __builtin_amdgcn_global_load_lds(AS1(Ah + aoff), AS3((char*)lAh + ldsOff), 16, 0, 0);
      __builtin_amdgcn_global_load_lds(AS1(Al + aoff), AS3((char*)lAl + ldsOff), 16, 0, 0);
      __builtin_amdgcn_global_load_lds(AS1(Bh + boff), AS3((char*)lBh + ldsOff), 16, 0, 0);
      __builtin_amdgcn_global_load_lds(AS1(Bl + boff), AS3((char*)lBl + ldsOff), 16, 0, 0);
    }
    __syncthreads();
    bf16x8 ah[4], al[4], bh[4], bl[4];
#pragma unroll
    for (int rb = 0; rb < 4; ++rb) {
      ah[rb] = *(const bf16x8*)(lAh + (wr + rb * 16 + m) * 32 + ko);
      al[rb] = *(const bf16x8*)(lAl + (wr + rb * 16 + m) * 32 + ko);
    }
#pragma unroll
    for (int cb = 0; cb < 4; ++cb) {
      bh[cb] = *(const bf16x8*)(lBh + (wc + cb * 16 + m) * 32 + ko);
      bl[cb] = *(const bf16x8*)(lBl + (wc + cb * 16 + m) * 32 + ko);
    }
#pragma unroll
    for (int rb = 0; rb < 4; ++rb)
#pragma unroll
      for (int cb = 0; cb < 4; ++cb) {
        acc[rb][cb] = __builtin_amdgcn_mfma_f32_16x16x32_bf16(ah[rb], bh[cb], acc[rb][cb], 0, 0, 0);
        acc[rb][cb] = __builtin_amdgcn_mfma_f32_16x16x32_bf16(ah[rb], bl[cb], acc[rb][cb], 0, 0, 0);
        acc[rb][cb] = __builtin_amdgcn_mfma_f32_16x16x32_bf16(al[rb], bh[cb], acc[rb][cb], 0, 0, 0);
      }
    __syncthreads();
  }

  const int crow0 = rowTile + wr + (lane >> 4) * 4;
  const int ccol0 = colTile + wc + (lane & 15);
#pragma unroll
  for (int rb = 0; rb < 4; ++rb)
#pragma unroll
    for (int cb = 0; cb < 4; ++cb)
#pragma unroll
      for (int r = 0; r < 4; ++r)
        C[(size_t)(crow0 + rb * 16 + r) * N + ccol0 + cb * 16] = acc[rb][cb][r];
}

// ---------------- S partial (fp32 q,k): S[h][d][e] += sum_n k[n,d]*q[n,e] ----------------
#define SPLIT 8
__global__ __launch_bounds__(256) void s_partial(const float* __restrict__ QK,
                                                 float* __restrict__ Spart) {
  const int h  = blockIdx.x;           // 16 heads (one batch)
  const int sp = blockIdx.y;
  const int tid = threadIdx.x;
  __shared__ __align__(16) float ktile[64 * 64];
  __shared__ __align__(16) float qtile[64 * 64];
  const int d0 = (tid >> 4) * 4;
  const int e0 = (tid & 15) * 4;
  float acc[4][4] = {};
  const size_t baseQ = (size_t)h * 64;          // cols [0,1024): q
  const size_t baseK = 1024 + (size_t)h * 64;   // cols [1024,2048): k

  const int t0beg = sp * (4096 / SPLIT);
  const int t0end = (sp + 1) * (4096 / SPLIT);
  for (int t0 = t0beg; t0 < t0end; t0 += 64) {
#pragma unroll
    for (int i = 0; i < 4; ++i) {
      int idx = i * 256 + tid;
      int tok = idx >> 4;
      int c4  = (idx & 15) * 4;       // float index within 64-float row
      int ldsOff = (i * 256 + (tid & 192)) * 16;
      __builtin_amdgcn_global_load_lds(AS1(QK + (size_t)(t0 + tok) * 2048 + baseK + c4),
                                       AS3((char*)ktile + ldsOff), 16, 0, 0);
      __builtin_amdgcn_global_load_lds(AS1(QK + (size_t)(t0 + tok) * 2048 + baseQ + c4),
                                       AS3((char*)qtile + ldsOff), 16, 0, 0);
    }
    __syncthreads();
#pragma unroll 4
    for (int n = 0; n < 64; ++n) {
      float4 kf = *(const float4*)(ktile + n * 64 + d0);
      float4 qf = *(const float4*)(qtile + n * 64 + e0);
      float kk[4] = { kf.x, kf.y, kf.z, kf.w };
      float qq[4] = { qf.x, qf.y, qf.z, qf.w };
#pragma unroll
      for (int i = 0; i < 4; ++i)
#pragma unroll
        for (int j = 0; j < 4; ++j)
          acc[i][j] += kk[i] * qq[j];
    }
    __syncthreads();
  }
  float* out = Spart + ((size_t)sp * 16 + h) * 4096;
#pragma unroll
  for (int i = 0; i < 4; ++i)
#pragma unroll
    for (int j = 0; j < 4; ++j)
      out[(d0 + i) * 64 + e0 + j] = acc[i][j];
}

// ---------------- reduce partials + softmax rows -> attn bf16 (one batch) ----------------
__global__ __launch_bounds__(256) void softmax_kernel(const float* __restrict__ Spart,
                                                      const float* __restrict__ alpha,
                                                      u16* __restrict__ attn, int b) {
  const int row  = blockIdx.x * 4 + (threadIdx.x >> 6);  // 1024 rows = h*64 + d
  const int lane = threadIdx.x & 63;
  const int h = row >> 6, d = row & 63;
  const size_t off = (size_t)h * 4096 + d * 64 + lane;
  float s = 0.f;
#pragma unroll
  for (int sp = 0; sp < SPLIT; ++sp) s += Spart[(size_t)sp * 65536 + off];
  s /= alpha[h];
  float mx = s;
#pragma unroll
  for (int o = 32; o; o >>= 1) mx = fmaxf(mx, __shfl_xor(mx, o, 64));
  float e = __expf(s - mx);
  float sm = e;
#pragma unroll
  for (int o = 32; o; o >>= 1) sm += __shfl_xor(sm, o, 64);
  attn[(size_t)b * 65536 + off] = f2bf(e / sm);
}

// ---------------- out_mid[m][h*64+dd] = sum_e attn[bh][dd][e] * v[m][e] (MFMA) ----------------
__global__ __launch_bounds__(256) void attnv_kernel(const u16* __restrict__ V,
                                                    const u16* __restrict__ attn,
                                                    u16* __restrict__ outmid) {
  const int tile = blockIdx.x;   // 64-token tile over b*n (0..255)
  const int h    = blockIdx.y;
  const int tid = threadIdx.x, lane = tid & 63, wave = tid >> 6;
  const int b = (tile * 64) >> 12;
  const int bh = b * 16 + h;
  __shared__ __align__(16) u16 vt[64 * 64];
  __shared__ __align__(16) u16 at[64 * 64];
  const size_t baseV = (size_t)tile * 64 * 1024 + (size_t)h * 64;
#pragma unroll
  for (int i = 0; i < 2; ++i) {
    int idx = i * 256 + tid;
    int tok = idx >> 3;
    int c8  = (idx & 7) * 8;
    int ldsOff = (i * 256 + (tid & 192)) * 16;
    __builtin_amdgcn_global_load_lds(AS1(V + baseV + (size_t)tok * 1024 + c8),
                                     AS3((char*)vt + ldsOff), 16, 0, 0);
    __builtin_amdgcn_global_load_lds(AS1(attn + (size_t)bh * 4096 + idx * 8),
                                     AS3((char*)at + ldsOff), 16, 0, 0);
  }
  __syncthreads();
  const int m  = lane & 15;
  const int ko = (lane >> 4) * 8;
  f32x4 acc[4] = {};
#pragma unroll
  for (int ks = 0; ks < 2; ++ks) {
    bf16x8 a = *(const bf16x8*)(vt + (wave * 16 + m) * 64 + ks * 32 + ko);
#pragma unroll
    for (int cb = 0; cb < 4; ++cb) {
      bf16x8 bb = *(const bf16x8*)(at + (cb * 16 + m) * 64 + ks * 32 + ko);
      acc[cb] = __builtin_amdgcn_mfma_f32_16x16x32_bf16(a, bb, acc[cb], 0, 0, 0);
    }
  }
#pragma unroll
  for (int cb = 0; cb < 4; ++cb) {
    int col = h * 64 + cb * 16 + (lane & 15);
#pragma unroll
    for (int r = 0; r < 4; ++r) {
      int row = tile * 64 + wave * 16 + (lane >> 4) * 4 + r;
      outmid[(size_t)row * 1024 + col] = f2bf(acc[cb][r]);
    }
  }
}

extern "C" void kernel_launch(void* const* d_in, const int* in_sizes, int n_in,
                              void* d_out, int out_size, void* d_ws, size_t ws_size,
                              hipStream_t stream) {
  const float* x     = (const float*)d_in[0];
  // d_in[1] = H, d_in[2] = W (unused scalars)
  const float* Wqkv  = (const float*)d_in[3];
  const float* Wproj = (const float*)d_in[4];
  const float* bproj = (const float*)d_in[5];
  const float* alpha = (const float*)d_in[6];

  char* ws = (char*)d_ws;
  u16*   Xhi   = (u16*)ws;                        // 16M elems, 33.55 MB
  u16*   Xlo   = (u16*)(ws + 33554432);           // 33.55 MB
  u16*   Wqh   = (u16*)(ws + 67108864);           // 3M elems, 6.29 MB
  u16*   Wql   = (u16*)(ws + 73400320);           // 6.29 MB
  u16*   Wpb   = (u16*)(ws + 79691776);           // 1M elems, 2.10 MB
  u16*   Vb    = (u16*)(ws + 81788928);           // 16384x1024 bf16, 33.55 MB
  float* QKb   = (float*)(ws + 115343360);        // 4096x2048 fp32, 33.55 MB (per-batch)
  float* Spart = (float*)(ws + 148897792);        // 8x16x4096 fp32, 2.10 MB
  u16*   attnb = (u16*)(ws + 150994944);          // 64x4096 bf16, 0.52 MB
  u16*   outmid = Xhi;                            // Xhi dead after QK/V GEMMs

  // fp32 -> bf16 hi/lo splits
  convert_split_kernel<<<1024, 256, 0, stream>>>(x,    Xhi, Xlo, 16777216 / 4);
  convert_split_kernel<<<256,  256, 0, stream>>>(Wqkv, Wqh, Wql, 3145728 / 4);
  convert_kernel<<<128, 256, 0, stream>>>(Wproj, Wpb, 1048576 / 4);

  // V = X @ Wv^T  (single bf16, benign error path)  [16384 x 1024]
  gemm_bt<true, false><<<dim3(128, 8), 256, 0, stream>>>(
      Xhi, Wqh + (size_t)2048 * 1024, Vb, nullptr, 16384, 1024, 1024);

  // Per batch: high-precision QK (fp32 out), S partials, softmax -> attn
  for (int b = 0; b < 4; ++b) {
    gemm_qk_split<<<dim3(32, 16), 256, 0, stream>>>(
        Xhi + (size_t)b * 4096 * 1024, Xlo + (size_t)b * 4096 * 1024,
        Wqh, Wql, QKb, 4096, 2048, 1024);
    s_partial<<<dim3(16, SPLIT), 256, 0, stream>>>(QKb, Spart);
    softmax_kernel<<<256, 256, 0, stream>>>(Spart, alpha, attnb, b);
  }

  // out_mid = attn @ V^T per (b,h)
  attnv_kernel<<<dim3(256, 16), 256, 0, stream>>>(Vb, attnb, outmid);
  // Y = out_mid @ Wproj^T + bproj  [16384 x 1024] fp32
  gemm_bt<false, true><<<dim3(128, 8), 256, 0, stream>>>(
      outmid, Wpb, d_out, bproj, 16384, 1024, 1024);
}

// Round 3
// 465.422 us; speedup vs baseline: 1.2600x; 1.2600x over previous
//
#include <hip/hip_runtime.h>
#include <hip/hip_bf16.h>
#include <cstdint>
#include <cstddef>

typedef unsigned short u16;
typedef __bf16 bf16x8 __attribute__((ext_vector_type(8)));
typedef float f32x4 __attribute__((ext_vector_type(4)));
typedef unsigned short u16x4 __attribute__((ext_vector_type(4)));

#define AS1(p) ((__attribute__((address_space(1))) void*)(p))
#define AS3(p) ((__attribute__((address_space(3))) void*)(p))

__device__ __forceinline__ float bf2f(u16 u) {
  unsigned v = ((unsigned)u) << 16; float f; __builtin_memcpy(&f, &v, 4); return f;
}
__device__ __forceinline__ u16 f2bf(float f) {
  unsigned u; __builtin_memcpy(&u, &f, 4);
  u += 0x7FFFu + ((u >> 16) & 1u);   // RNE
  return (u16)(u >> 16);
}

// ---------------- fp32 -> bf16 convert (plain) ----------------
__global__ __launch_bounds__(256) void convert_kernel(const float* __restrict__ src,
                                                      u16* __restrict__ dst, int n4) {
  int i = blockIdx.x * blockDim.x + threadIdx.x;
  int stride = gridDim.x * blockDim.x;
  for (; i < n4; i += stride) {
    float4 v = ((const float4*)src)[i];
    u16x4 o;
    o.x = f2bf(v.x); o.y = f2bf(v.y); o.z = f2bf(v.z); o.w = f2bf(v.w);
    ((u16x4*)dst)[i] = o;
  }
}

// ---------------- fp32 -> bf16 hi + lo split ----------------
__global__ __launch_bounds__(256) void convert_split_kernel(const float* __restrict__ src,
                                                            u16* __restrict__ hi,
                                                            u16* __restrict__ lo, int n4) {
  int i = blockIdx.x * blockDim.x + threadIdx.x;
  int stride = gridDim.x * blockDim.x;
  for (; i < n4; i += stride) {
    float4 v = ((const float4*)src)[i];
    u16x4 oh, ol;
    oh.x = f2bf(v.x); ol.x = f2bf(v.x - bf2f(oh.x));
    oh.y = f2bf(v.y); ol.y = f2bf(v.y - bf2f(oh.y));
    oh.z = f2bf(v.z); ol.z = f2bf(v.z - bf2f(oh.z));
    oh.w = f2bf(v.w); ol.w = f2bf(v.w - bf2f(oh.w));
    ((u16x4*)hi)[i] = oh;
    ((u16x4*)lo)[i] = ol;
  }
}

// ---------------- transpose + split: x[b,n,c] fp32 -> Xb[b,n,c] bf16, XT{hi,lo}[b,c,n] ----------------
__global__ __launch_bounds__(256) void transpose_split_kernel(const float* __restrict__ x,
                                                              u16* __restrict__ Xb,
                                                              u16* __restrict__ XThi,
                                                              u16* __restrict__ XTlo) {
  __shared__ u16 lhi[64 * 68];   // pad 68: 8B-aligned transposed reads, ~4-way write conflicts
  __shared__ u16 llo[64 * 68];
  const int t  = threadIdx.x;
  const int nT = blockIdx.x, cT = blockIdx.y, b = blockIdx.z;
  const size_t xbase = ((size_t)b * 4096 + nT * 64) * 1024 + cT * 64;
  const int c4 = (t & 15) * 4;
  const int r0 = t >> 4;
#pragma unroll
  for (int j = 0; j < 4; ++j) {
    int r = r0 + j * 16;
    float4 v = *(const float4*)(x + xbase + (size_t)r * 1024 + c4);
    u16x4 hi;
    hi.x = f2bf(v.x); hi.y = f2bf(v.y); hi.z = f2bf(v.z); hi.w = f2bf(v.w);
    *(u16x4*)(Xb + xbase + (size_t)r * 1024 + c4) = hi;
    u16 lo[4];
    lo[0] = f2bf(v.x - bf2f(hi.x)); lo[1] = f2bf(v.y - bf2f(hi.y));
    lo[2] = f2bf(v.z - bf2f(hi.z)); lo[3] = f2bf(v.w - bf2f(hi.w));
    u16 hia[4] = { hi.x, hi.y, hi.z, hi.w };
#pragma unroll
    for (int i = 0; i < 4; ++i) {
      lhi[(c4 + i) * 68 + r] = hia[i];
      llo[(c4 + i) * 68 + r] = lo[i];
    }
  }
  __syncthreads();
  const int c  = t >> 2;
  const int n0 = (t & 3) * 16;
  const size_t tbase = ((size_t)b * 1024 + cT * 64 + c) * 4096 + nT * 64 + n0;
#pragma unroll
  for (int q = 0; q < 4; ++q) {
    *(u16x4*)(XThi + tbase + q * 4) = *(const u16x4*)(lhi + c * 68 + n0 + q * 4);
    *(u16x4*)(XTlo + tbase + q * 4) = *(const u16x4*)(llo + c * 68 + n0 + q * 4);
  }
}

// ---------------- m97-style GEMM: C[M,N] = A[M,K] * B[N,K]^T (single bf16) ----------------
template<bool OUT_BF16, bool HAS_BIAS>
__global__ __launch_bounds__(256) void gemm_bt(const u16* __restrict__ A,
                                               const u16* __restrict__ B,
                                               void* __restrict__ Cv,
                                               const float* __restrict__ bias,
                                               int M, int N, int K) {
  __shared__ __align__(16) u16 lA[128 * 32];
  __shared__ __align__(16) u16 lB[128 * 32];
  const int tid  = threadIdx.x;
  const int lane = tid & 63;
  const int wave = tid >> 6;
  const int rowTile = blockIdx.x * 128;
  const int colTile = blockIdx.y * 128;
  const int wr = (wave >> 1) * 64;
  const int wc = (wave & 1) * 64;

  f32x4 acc[4][4] = {};
  const int m  = lane & 15;
  const int ko = (lane >> 4) * 8;

  for (int kt = 0; kt < K; kt += 32) {
#pragma unroll
    for (int i = 0; i < 2; ++i) {
      int idx = i * 256 + tid;
      int row = idx >> 2;
      int kc  = (idx & 3) * 8;
      int ldsOff = (i * 256 + (tid & 192)) * 16;
      __builtin_amdgcn_global_load_lds(AS1(A + (size_t)(rowTile + row) * K + kt + kc),
                                       AS3((char*)lA + ldsOff), 16, 0, 0);
      __builtin_amdgcn_global_load_lds(AS1(B + (size_t)(colTile + row) * K + kt + kc),
                                       AS3((char*)lB + ldsOff), 16, 0, 0);
    }
    __syncthreads();
    bf16x8 af[4], bfr[4];
#pragma unroll
    for (int rb = 0; rb < 4; ++rb)
      af[rb] = *(const bf16x8*)(lA + (wr + rb * 16 + m) * 32 + ko);
#pragma unroll
    for (int cb = 0; cb < 4; ++cb)
      bfr[cb] = *(const bf16x8*)(lB + (wc + cb * 16 + m) * 32 + ko);
#pragma unroll
    for (int rb = 0; rb < 4; ++rb)
#pragma unroll
      for (int cb = 0; cb < 4; ++cb)
        acc[rb][cb] = __builtin_amdgcn_mfma_f32_16x16x32_bf16(af[rb], bfr[cb], acc[rb][cb], 0, 0, 0);
    __syncthreads();
  }

  const int crow0 = rowTile + wr + (lane >> 4) * 4;
  const int ccol0 = colTile + wc + (lane & 15);
#pragma unroll
  for (int rb = 0; rb < 4; ++rb) {
#pragma unroll
    for (int cb = 0; cb < 4; ++cb) {
      int col = ccol0 + cb * 16;
      float bv = HAS_BIAS ? bias[col] : 0.f;
#pragma unroll
      for (int r = 0; r < 4; ++r) {
        int row = crow0 + rb * 16 + r;
        float v = acc[rb][cb][r] + bv;
        if (OUT_BF16) ((u16*)Cv)[(size_t)row * N + col] = f2bf(v);
        else          ((float*)Cv)[(size_t)row * N + col] = v;
      }
    }
  }
}

// ---------------- Gram GEMM: Gpart = XT_b * XT_b^T over half-K, split x3 ----------------
// XT layout [b][1024][4096] bf16. blockIdx.z: b = z>>1, kh = z&1. Out fp32 [kh*4+b][1024][1024].
__global__ __launch_bounds__(256) void gemm_gram(const u16* __restrict__ XThi,
                                                 const u16* __restrict__ XTlo,
                                                 float* __restrict__ Gpart) {
  __shared__ __align__(16) u16 lAh[128 * 32];
  __shared__ __align__(16) u16 lAl[128 * 32];
  __shared__ __align__(16) u16 lBh[128 * 32];
  __shared__ __align__(16) u16 lBl[128 * 32];
  const int tid  = threadIdx.x;
  const int lane = tid & 63;
  const int wave = tid >> 6;
  const int rowTile = blockIdx.x * 128;
  const int colTile = blockIdx.y * 128;
  const int b  = blockIdx.z >> 1;
  const int kh = blockIdx.z & 1;
  const int wr = (wave >> 1) * 64;
  const int wc = (wave & 1) * 64;

  const u16* Ah = XThi + ((size_t)b << 22);
  const u16* Al = XTlo + ((size_t)b << 22);

  f32x4 acc[4][4] = {};
  const int m  = lane & 15;
  const int ko = (lane >> 4) * 8;

  const int k0 = kh * 2048;
  for (int kt = k0; kt < k0 + 2048; kt += 32) {
#pragma unroll
    for (int i = 0; i < 2; ++i) {
      int idx = i * 256 + tid;
      int row = idx >> 2;
      int kc  = (idx & 3) * 8;
      int ldsOff = (i * 256 + (tid & 192)) * 16;
      size_t aoff = (size_t)(rowTile + row) * 4096 + kt + kc;
      size_t boff = (size_t)(colTile + row) * 4096 + kt + kc;
      __builtin_amdgcn_global_load_lds(AS1(Ah + aoff), AS3((char*)lAh + ldsOff), 16, 0, 0);
      __builtin_amdgcn_global_load_lds(AS1(Al + aoff), AS3((char*)lAl + ldsOff), 16, 0, 0);
      __builtin_amdgcn_global_load_lds(AS1(Ah + boff), AS3((char*)lBh + ldsOff), 16, 0, 0);
      __builtin_amdgcn_global_load_lds(AS1(Al + boff), AS3((char*)lBl + ldsOff), 16, 0, 0);
    }
    __syncthreads();
    bf16x8 ah[4], al[4], bh[4], bl[4];
#pragma unroll
    for (int rb = 0; rb < 4; ++rb) {
      ah[rb] = *(const bf16x8*)(lAh + (wr + rb * 16 + m) * 32 + ko);
      al[rb] = *(const bf16x8*)(lAl + (wr + rb * 16 + m) * 32 + ko);
    }
#pragma unroll
    for (int cb = 0; cb < 4; ++cb) {
      bh[cb] = *(const bf16x8*)(lBh + (wc + cb * 16 + m) * 32 + ko);
      bl[cb] = *(const bf16x8*)(lBl + (wc + cb * 16 + m) * 32 + ko);
    }
#pragma unroll
    for (int rb = 0; rb < 4; ++rb)
#pragma unroll
      for (int cb = 0; cb < 4; ++cb) {
        acc[rb][cb] = __builtin_amdgcn_mfma_f32_16x16x32_bf16(ah[rb], bh[cb], acc[rb][cb], 0, 0, 0);
        acc[rb][cb] = __builtin_amdgcn_mfma_f32_16x16x32_bf16(ah[rb], bl[cb], acc[rb][cb], 0, 0, 0);
        acc[rb][cb] = __builtin_amdgcn_mfma_f32_16x16x32_bf16(al[rb], bh[cb], acc[rb][cb], 0, 0, 0);
      }
    __syncthreads();
  }

  float* out = Gpart + ((size_t)(kh * 4 + b) << 20);
  const int crow0 = rowTile + wr + (lane >> 4) * 4;
  const int ccol0 = colTile + wc + (lane & 15);
#pragma unroll
  for (int rb = 0; rb < 4; ++rb)
#pragma unroll
    for (int cb = 0; cb < 4; ++cb)
#pragma unroll
      for (int r = 0; r < 4; ++r)
        out[(size_t)(crow0 + rb * 16 + r) * 1024 + ccol0 + cb * 16] = acc[rb][cb][r];
}

// ---------------- reduce G partials + split to bf16 hi/lo ----------------
__global__ __launch_bounds__(256) void gram_reduce_split(const float* __restrict__ Gp,
                                                         u16* __restrict__ Ghi,
                                                         u16* __restrict__ Glo) {
  int i = blockIdx.x * 256 + threadIdx.x;
  int stride = gridDim.x * 256;
  for (; i < 1048576; i += stride) {
    float4 a = ((const float4*)Gp)[i];
    float4 c = ((const float4*)(Gp + 4194304))[i];
    float s[4] = { a.x + c.x, a.y + c.y, a.z + c.z, a.w + c.w };
    u16x4 oh, ol;
    oh.x = f2bf(s[0]); ol.x = f2bf(s[0] - bf2f(oh.x));
    oh.y = f2bf(s[1]); ol.y = f2bf(s[1] - bf2f(oh.y));
    oh.z = f2bf(s[2]); ol.z = f2bf(s[2] - bf2f(oh.z));
    oh.w = f2bf(s[3]); ol.w = f2bf(s[3] - bf2f(oh.w));
    ((u16x4*)Ghi)[i] = oh;
    ((u16x4*)Glo)[i] = ol;
  }
}

// ---------------- T' = Wq * G^T (G symmetric) per batch, split x3, split-bf16 out ----------------
// C[e,c1] = sum_c2 Wq[e,c2] G[b][c1,c2].  Grid (8,8,4).
__global__ __launch_bounds__(256) void gemm_tprime(const u16* __restrict__ Wqh,
                                                   const u16* __restrict__ Wql,
                                                   const u16* __restrict__ Ghi,
                                                   const u16* __restrict__ Glo,
                                                   u16* __restrict__ Tph,
                                                   u16* __restrict__ Tpl) {
  __shared__ __align__(16) u16 lAh[128 * 32];
  __shared__ __align__(16) u16 lAl[128 * 32];
  __shared__ __align__(16) u16 lBh[128 * 32];
  __shared__ __align__(16) u16 lBl[128 * 32];
  const int tid  = threadIdx.x;
  const int lane = tid & 63;
  const int wave = tid >> 6;
  const int rowTile = blockIdx.x * 128;
  const int colTile = blockIdx.y * 128;
  const size_t zoff = (size_t)blockIdx.z << 20;
  const int wr = (wave >> 1) * 64;
  const int wc = (wave & 1) * 64;

  f32x4 acc[4][4] = {};
  const int m  = lane & 15;
  const int ko = (lane >> 4) * 8;

  for (int kt = 0; kt < 1024; kt += 32) {
#pragma unroll
    for (int i = 0; i < 2; ++i) {
      int idx = i * 256 + tid;
      int row = idx >> 2;
      int kc  = (idx & 3) * 8;
      int ldsOff = (i * 256 + (tid & 192)) * 16;
      size_t aoff = (size_t)(rowTile + row) * 1024 + kt + kc;
      size_t boff = zoff + (size_t)(colTile + row) * 1024 + kt + kc;
      __builtin_amdgcn_global_load_lds(AS1(Wqh + aoff), AS3((char*)lAh + ldsOff), 16, 0, 0);
      __builtin_amdgcn_global_load_lds(AS1(Wql + aoff), AS3((char*)lAl + ldsOff), 16, 0, 0);
      __builtin_amdgcn_global_load_lds(AS1(Ghi + boff), AS3((char*)lBh + ldsOff), 16, 0, 0);
      __builtin_amdgcn_global_load_lds(AS1(Glo + boff), AS3((char*)lBl + ldsOff), 16, 0, 0);
    }
    __syncthreads();
    bf16x8 ah[4], al[4], bh[4], bl[4];
#pragma unroll
    for (int rb = 0; rb < 4; ++rb) {
      ah[rb] = *(const bf16x8*)(lAh + (wr + rb * 16 + m) * 32 + ko);
      al[rb] = *(const bf16x8*)(lAl + (wr + rb * 16 + m) * 32 + ko);
    }
#pragma unroll
    for (int cb = 0; cb < 4; ++cb) {
      bh[cb] = *(const bf16x8*)(lBh + (wc + cb * 16 + m) * 32 + ko);
      bl[cb] = *(const bf16x8*)(lBl + (wc + cb * 16 + m) * 32 + ko);
    }
#pragma unroll
    for (int rb = 0; rb < 4; ++rb)
#pragma unroll
      for (int cb = 0; cb < 4; ++cb) {
        acc[rb][cb] = __builtin_amdgcn_mfma_f32_16x16x32_bf16(ah[rb], bh[cb], acc[rb][cb], 0, 0, 0);
        acc[rb][cb] = __builtin_amdgcn_mfma_f32_16x16x32_bf16(ah[rb], bl[cb], acc[rb][cb], 0, 0, 0);
        acc[rb][cb] = __builtin_amdgcn_mfma_f32_16x16x32_bf16(al[rb], bh[cb], acc[rb][cb], 0, 0, 0);
      }
    __syncthreads();
  }

  const int crow0 = rowTile + wr + (lane >> 4) * 4;
  const int ccol0 = colTile + wc + (lane & 15);
#pragma unroll
  for (int rb = 0; rb < 4; ++rb)
#pragma unroll
    for (int cb = 0; cb < 4; ++cb)
#pragma unroll
      for (int r = 0; r < 4; ++r) {
        float v = acc[rb][cb][r];
        u16 hi = f2bf(v);
        u16 lo = f2bf(v - bf2f(hi));
        size_t off = zoff + (size_t)(crow0 + rb * 16 + r) * 1024 + ccol0 + cb * 16;
        Tph[off] = hi;
        Tpl[off] = lo;
      }
}

// ---------------- fused S + softmax: S[d,e] = sum_c1 Wk[hd,c1] T'[b][he,c1]; attn bf16 out ----------------
__global__ __launch_bounds__(256) void s_softmax_kernel(const u16* __restrict__ Wqh,
                                                        const u16* __restrict__ Wql,
                                                        const u16* __restrict__ Tph,
                                                        const u16* __restrict__ Tpl,
                                                        const float* __restrict__ alpha,
                                                        u16* __restrict__ attn) {
  const int h = blockIdx.x, b = blockIdx.y;
  const int tid = threadIdx.x, lane = tid & 63, wave = tid >> 6;
  __shared__ __align__(16) u16 lAh[64 * 32];
  __shared__ __align__(16) u16 lAl[64 * 32];
  __shared__ __align__(16) u16 lBh[64 * 32];
  __shared__ __align__(16) u16 lBl[64 * 32];

  const size_t aBase = (size_t)(1024 + h * 64) * 1024;          // Wk rows
  const size_t bBase = ((size_t)b << 20) + (size_t)(h * 64) * 1024;  // T' rows

  f32x4 acc[4] = {};
  const int m  = lane & 15;
  const int ko = (lane >> 4) * 8;
  const int srow = tid >> 2;
  const int skc  = (tid & 3) * 8;
  const int ldsOff = (tid & 192) * 16;

  for (int kt = 0; kt < 1024; kt += 32) {
    __builtin_amdgcn_global_load_lds(AS1(Wqh + aBase + (size_t)srow * 1024 + kt + skc),
                                     AS3((char*)lAh + ldsOff), 16, 0, 0);
    __builtin_amdgcn_global_load_lds(AS1(Wql + aBase + (size_t)srow * 1024 + kt + skc),
                                     AS3((char*)lAl + ldsOff), 16, 0, 0);
    __builtin_amdgcn_global_load_lds(AS1(Tph + bBase + (size_t)srow * 1024 + kt + skc),
                                     AS3((char*)lBh + ldsOff), 16, 0, 0);
    __builtin_amdgcn_global_load_lds(AS1(Tpl + bBase + (size_t)srow * 1024 + kt + skc),
                                     AS3((char*)lBl + ldsOff), 16, 0, 0);
    __syncthreads();
    bf16x8 ah = *(const bf16x8*)(lAh + (wave * 16 + m) * 32 + ko);
    bf16x8 al = *(const bf16x8*)(lAl + (wave * 16 + m) * 32 + ko);
#pragma unroll
    for (int cb = 0; cb < 4; ++cb) {
      bf16x8 bh = *(const bf16x8*)(lBh + (cb * 16 + m) * 32 + ko);
      bf16x8 bl = *(const bf16x8*)(lBl + (cb * 16 + m) * 32 + ko);
      acc[cb] = __builtin_amdgcn_mfma_f32_16x16x32_bf16(ah, bh, acc[cb], 0, 0, 0);
      acc[cb] = __builtin_amdgcn_mfma_f32_16x16x32_bf16(ah, bl, acc[cb], 0, 0, 0);
      acc[cb] = __builtin_amdgcn_mfma_f32_16x16x32_bf16(al, bh, acc[cb], 0, 0, 0);
    }
    __syncthreads();
  }

  const float invA = 1.f / alpha[h];
  const int g = lane >> 4;
  const size_t obase = (size_t)(b * 16 + h) * 4096;
#pragma unroll
  for (int r = 0; r < 4; ++r) {
    int d = wave * 16 + g * 4 + r;
    float s[4];
#pragma unroll
    for (int cb = 0; cb < 4; ++cb) s[cb] = acc[cb][r] * invA;
    float mx = fmaxf(fmaxf(s[0], s[1]), fmaxf(s[2], s[3]));
#pragma unroll
    for (int o = 1; o < 16; o <<= 1) mx = fmaxf(mx, __shfl_xor(mx, o, 64));
    float e[4]; float sum = 0.f;
#pragma unroll
    for (int cb = 0; cb < 4; ++cb) { e[cb] = __expf(s[cb] - mx); sum += e[cb]; }
#pragma unroll
    for (int o = 1; o < 16; o <<= 1) sum += __shfl_xor(sum, o, 64);
    float inv = 1.f / sum;
#pragma unroll
    for (int cb = 0; cb < 4; ++cb)
      attn[obase + (size_t)d * 64 + cb * 16 + (lane & 15)] = f2bf(e[cb] * inv);
  }
}

// ---------------- out_mid[n][h*64+dd] = sum_e attn[bh][dd][e] * v[n][he] (MFMA) ----------------
__global__ __launch_bounds__(256) void attnv_kernel(const u16* __restrict__ V,
                                                    const u16* __restrict__ attn,
                                                    u16* __restrict__ outmid) {
  const int tile = blockIdx.x;
  const int h    = blockIdx.y;
  const int tid = threadIdx.x, lane = tid & 63, wave = tid >> 6;
  const int b = (tile * 64) >> 12;
  const int bh = b * 16 + h;
  __shared__ __align__(16) u16 vt[64 * 64];
  __shared__ __align__(16) u16 at[64 * 64];
  const size_t baseV = (size_t)tile * 64 * 1024 + (size_t)h * 64;
#pragma unroll
  for (int i = 0; i < 2; ++i) {
    int idx = i * 256 + tid;
    int tok = idx >> 3;
    int c8  = (idx & 7) * 8;
    int ldsOff = (i * 256 + (tid & 192)) * 16;
    __builtin_amdgcn_global_load_lds(AS1(V + baseV + (size_t)tok * 1024 + c8),
                                     AS3((char*)vt + ldsOff), 16, 0, 0);
    __builtin_amdgcn_global_load_lds(AS1(attn + (size_t)bh * 4096 + idx * 8),
                                     AS3((char*)at + ldsOff), 16, 0, 0);
  }
  __syncthreads();
  const int m  = lane & 15;
  const int ko = (lane >> 4) * 8;
  f32x4 acc[4] = {};
#pragma unroll
  for (int ks = 0; ks < 2; ++ks) {
    bf16x8 a = *(const bf16x8*)(vt + (wave * 16 + m) * 64 + ks * 32 + ko);
#pragma unroll
    for (int cb = 0; cb < 4; ++cb) {
      bf16x8 bb = *(const bf16x8*)(at + (cb * 16 + m) * 64 + ks * 32 + ko);
      acc[cb] = __builtin_amdgcn_mfma_f32_16x16x32_bf16(a, bb, acc[cb], 0, 0, 0);
    }
  }
#pragma unroll
  for (int cb = 0; cb < 4; ++cb) {
    int col = h * 64 + cb * 16 + (lane & 15);
#pragma unroll
    for (int r = 0; r < 4; ++r) {
      int row = tile * 64 + wave * 16 + (lane >> 4) * 4 + r;
      outmid[(size_t)row * 1024 + col] = f2bf(acc[cb][r]);
    }
  }
}

extern "C" void kernel_launch(void* const* d_in, const int* in_sizes, int n_in,
                              void* d_out, int out_size, void* d_ws, size_t ws_size,
                              hipStream_t stream) {
  const float* x     = (const float*)d_in[0];
  const float* Wqkv  = (const float*)d_in[3];
  const float* Wproj = (const float*)d_in[4];
  const float* bproj = (const float*)d_in[5];
  const float* alpha = (const float*)d_in[6];

  char* ws = (char*)d_ws;
  // Region A (33.55 MB): Xb -> Gpart -> outmid (sequential lifetimes)
  u16*   Xb     = (u16*)ws;
  float* Gpart  = (float*)ws;
  u16*   outmid = (u16*)ws;
  // Region B (33.55 MB): XThi -> attn
  u16*   XThi  = (u16*)(ws + 33554432);
  u16*   attnb = (u16*)(ws + 33554432);
  // Region C (33.55 MB): XTlo -> {Ghi, Glo, Tph, Tpl}
  u16*   XTlo  = (u16*)(ws + 67108864);
  u16*   Ghi   = (u16*)(ws + 67108864);
  u16*   Glo   = (u16*)(ws + 75497472);
  u16*   Tph   = (u16*)(ws + 83886080);
  u16*   Tpl   = (u16*)(ws + 92274688);
  u16*   Wqh   = (u16*)(ws + 100663296);
  u16*   Wql   = (u16*)(ws + 106954752);
  u16*   Vb    = (u16*)(ws + 113246208);
  u16*   Wpb   = (u16*)(ws + 146800640);   // end: 148.9 MB

  // 1. x -> Xb (bf16 row-major) + XThi/XTlo (bf16, transposed per batch)
  transpose_split_kernel<<<dim3(64, 16, 4), 256, 0, stream>>>(x, Xb, XThi, XTlo);
  // 2. weight converts
  convert_split_kernel<<<256, 256, 0, stream>>>(Wqkv, Wqh, Wql, 3145728 / 4);
  convert_kernel<<<128, 256, 0, stream>>>(Wproj, Wpb, 1048576 / 4);
  // 3. V = X @ Wv^T  (single bf16)
  gemm_bt<true, false><<<dim3(128, 8), 256, 0, stream>>>(
      Xb, Wqh + (size_t)2048 * 1024, Vb, nullptr, 16384, 1024, 1024);
  // 4. G partials = XT_b XT_b^T, split-K=2  (overwrites Xb -> must follow step 3)
  gemm_gram<<<dim3(8, 8, 8), 256, 0, stream>>>(XThi, XTlo, Gpart);
  // 5. reduce + split G -> Ghi/Glo (overwrites XTlo region)
  gram_reduce_split<<<1024, 256, 0, stream>>>(Gpart, Ghi, Glo);
  // 6. T' = Wq G (symmetric), split-bf16 out
  gemm_tprime<<<dim3(8, 8, 4), 256, 0, stream>>>(Wqh, Wql, Ghi, Glo, Tph, Tpl);
  // 7. fused S + softmax -> attn (overwrites XThi region)
  s_softmax_kernel<<<dim3(16, 4), 256, 0, stream>>>(Wqh, Wql, Tph, Tpl, alpha, attnb);
  // 8. out_mid = attn @ V^T per (b,h)  (overwrites Gpart region)
  attnv_kernel<<<dim3(256, 16), 256, 0, stream>>>(Vb, attnb, outmid);
  // 9. Y = out_mid @ Wproj^T + bproj (fp32 out)
  gemm_bt<false, true><<<dim3(128, 8), 256, 0, stream>>>(
      outmid, Wpb, d_out, bproj, 16384, 1024, 1024);
}

// Round 4
// 451.638 us; speedup vs baseline: 1.2985x; 1.0305x over previous
//
#include <hip/hip_runtime.h>
#include <hip/hip_bf16.h>
#include <cstdint>
#include <cstddef>

typedef unsigned short u16;
typedef __bf16 bf16x8 __attribute__((ext_vector_type(8)));
typedef float f32x4 __attribute__((ext_vector_type(4)));
typedef unsigned short u16x4 __attribute__((ext_vector_type(4)));

#define AS1(p) ((__attribute__((address_space(1))) void*)(p))
#define AS3(p) ((__attribute__((address_space(3))) void*)(p))

__device__ __forceinline__ float bf2f(u16 u) {
  unsigned v = ((unsigned)u) << 16; float f; __builtin_memcpy(&f, &v, 4); return f;
}
__device__ __forceinline__ u16 f2bf(float f) {
  unsigned u; __builtin_memcpy(&u, &f, 4);
  u += 0x7FFFu + ((u >> 16) & 1u);   // RNE
  return (u16)(u >> 16);
}

// ---------------- fp32 -> bf16 convert (plain) ----------------
__global__ __launch_bounds__(256) void convert_kernel(const float* __restrict__ src,
                                                      u16* __restrict__ dst, int n4) {
  int i = blockIdx.x * blockDim.x + threadIdx.x;
  int stride = gridDim.x * blockDim.x;
  for (; i < n4; i += stride) {
    float4 v = ((const float4*)src)[i];
    u16x4 o;
    o.x = f2bf(v.x); o.y = f2bf(v.y); o.z = f2bf(v.z); o.w = f2bf(v.w);
    ((u16x4*)dst)[i] = o;
  }
}

// ---------------- fp32 -> bf16 hi + lo split ----------------
__global__ __launch_bounds__(256) void convert_split_kernel(const float* __restrict__ src,
                                                            u16* __restrict__ hi,
                                                            u16* __restrict__ lo, int n4) {
  int i = blockIdx.x * blockDim.x + threadIdx.x;
  int stride = gridDim.x * blockDim.x;
  for (; i < n4; i += stride) {
    float4 v = ((const float4*)src)[i];
    u16x4 oh, ol;
    oh.x = f2bf(v.x); ol.x = f2bf(v.x - bf2f(oh.x));
    oh.y = f2bf(v.y); ol.y = f2bf(v.y - bf2f(oh.y));
    oh.z = f2bf(v.z); ol.z = f2bf(v.z - bf2f(oh.z));
    oh.w = f2bf(v.w); ol.w = f2bf(v.w - bf2f(oh.w));
    ((u16x4*)hi)[i] = oh;
    ((u16x4*)lo)[i] = ol;
  }
}

// ---------------- transpose + split: x[b,n,c] fp32 -> Xb[b,n,c] bf16, XT{hi,lo}[b,c,n] ----------------
__global__ __launch_bounds__(256) void transpose_split_kernel(const float* __restrict__ x,
                                                              u16* __restrict__ Xb,
                                                              u16* __restrict__ XThi,
                                                              u16* __restrict__ XTlo) {
  __shared__ u16 lhi[64 * 68];
  __shared__ u16 llo[64 * 68];
  const int t  = threadIdx.x;
  const int nT = blockIdx.x, cT = blockIdx.y, b = blockIdx.z;
  const size_t xbase = ((size_t)b * 4096 + nT * 64) * 1024 + cT * 64;
  const int c4 = (t & 15) * 4;
  const int r0 = t >> 4;
#pragma unroll
  for (int j = 0; j < 4; ++j) {
    int r = r0 + j * 16;
    float4 v = *(const float4*)(x + xbase + (size_t)r * 1024 + c4);
    u16x4 hi;
    hi.x = f2bf(v.x); hi.y = f2bf(v.y); hi.z = f2bf(v.z); hi.w = f2bf(v.w);
    *(u16x4*)(Xb + xbase + (size_t)r * 1024 + c4) = hi;
    u16 lo[4];
    lo[0] = f2bf(v.x - bf2f(hi.x)); lo[1] = f2bf(v.y - bf2f(hi.y));
    lo[2] = f2bf(v.z - bf2f(hi.z)); lo[3] = f2bf(v.w - bf2f(hi.w));
    u16 hia[4] = { hi.x, hi.y, hi.z, hi.w };
#pragma unroll
    for (int i = 0; i < 4; ++i) {
      lhi[(c4 + i) * 68 + r] = hia[i];
      llo[(c4 + i) * 68 + r] = lo[i];
    }
  }
  __syncthreads();
  const int c  = t >> 2;
  const int n0 = (t & 3) * 16;
  const size_t tbase = ((size_t)b * 1024 + cT * 64 + c) * 4096 + nT * 64 + n0;
#pragma unroll
  for (int q = 0; q < 4; ++q) {
    *(u16x4*)(XThi + tbase + q * 4) = *(const u16x4*)(lhi + c * 68 + n0 + q * 4);
    *(u16x4*)(XTlo + tbase + q * 4) = *(const u16x4*)(llo + c * 68 + n0 + q * 4);
  }
}

// ---------------- m97-style GEMM: C[M,N] = A[M,K] * B[N,K]^T (single bf16) ----------------
template<bool OUT_BF16, bool HAS_BIAS>
__global__ __launch_bounds__(256) void gemm_bt(const u16* __restrict__ A,
                                               const u16* __restrict__ B,
                                               void* __restrict__ Cv,
                                               const float* __restrict__ bias,
                                               int M, int N, int K) {
  __shared__ __align__(16) u16 lA[128 * 32];
  __shared__ __align__(16) u16 lB[128 * 32];
  const int tid  = threadIdx.x;
  const int lane = tid & 63;
  const int wave = tid >> 6;
  const int rowTile = blockIdx.x * 128;
  const int colTile = blockIdx.y * 128;
  const int wr = (wave >> 1) * 64;
  const int wc = (wave & 1) * 64;

  f32x4 acc[4][4] = {};
  const int m  = lane & 15;
  const int ko = (lane >> 4) * 8;

  for (int kt = 0; kt < K; kt += 32) {
#pragma unroll
    for (int i = 0; i < 2; ++i) {
      int idx = i * 256 + tid;
      int row = idx >> 2;
      int kc  = (idx & 3) * 8;
      int ldsOff = (i * 256 + (tid & 192)) * 16;
      __builtin_amdgcn_global_load_lds(AS1(A + (size_t)(rowTile + row) * K + kt + kc),
                                       AS3((char*)lA + ldsOff), 16, 0, 0);
      __builtin_amdgcn_global_load_lds(AS1(B + (size_t)(colTile + row) * K + kt + kc),
                                       AS3((char*)lB + ldsOff), 16, 0, 0);
    }
    __syncthreads();
    bf16x8 af[4], bfr[4];
#pragma unroll
    for (int rb = 0; rb < 4; ++rb)
      af[rb] = *(const bf16x8*)(lA + (wr + rb * 16 + m) * 32 + ko);
#pragma unroll
    for (int cb = 0; cb < 4; ++cb)
      bfr[cb] = *(const bf16x8*)(lB + (wc + cb * 16 + m) * 32 + ko);
#pragma unroll
    for (int rb = 0; rb < 4; ++rb)
#pragma unroll
      for (int cb = 0; cb < 4; ++cb)
        acc[rb][cb] = __builtin_amdgcn_mfma_f32_16x16x32_bf16(af[rb], bfr[cb], acc[rb][cb], 0, 0, 0);
    __syncthreads();
  }

  const int crow0 = rowTile + wr + (lane >> 4) * 4;
  const int ccol0 = colTile + wc + (lane & 15);
#pragma unroll
  for (int rb = 0; rb < 4; ++rb) {
#pragma unroll
    for (int cb = 0; cb < 4; ++cb) {
      int col = ccol0 + cb * 16;
      float bv = HAS_BIAS ? bias[col] : 0.f;
#pragma unroll
      for (int r = 0; r < 4; ++r) {
        int row = crow0 + rb * 16 + r;
        float v = acc[rb][cb][r] + bv;
        if (OUT_BF16) ((u16*)Cv)[(size_t)row * N + col] = f2bf(v);
        else          ((float*)Cv)[(size_t)row * N + col] = v;
      }
    }
  }
}

// ---------------- symmetric Gram: Gpart[slice][b] partials of XT_b XT_b^T, split x3 ----------------
// 128 jobs/batch: j<112: strict-upper pair p=j>>2, kq=j&3. kq<2 -> tile (i,jj), kq>=2 -> tile (jj,i).
// slice = kq&1, K-range = kq*1024, len 1024.  j>=112: diag dd, kh=j&1, K len 2048, slice kh.
// Each per-kq partial P is symmetric (HH^T + HL^T + LH^T), so
// G(i,j) = s0(i,j)+s1(i,j)+s0(j,i)^T+s1(j,i)^T exactly; diag tiles: s0+s1 = full K.
__global__ __launch_bounds__(256) void gemm_gram(const u16* __restrict__ XThi,
                                                 const u16* __restrict__ XTlo,
                                                 float* __restrict__ Gpart) {
  const int job = blockIdx.x;
  const int b   = blockIdx.y;
  int rt, ct, k0, klen, slice;
  if (job < 112) {
    int p = job >> 2, kq = job & 3;
    int i = 0, rem = p;
    while (rem >= 7 - i) { rem -= 7 - i; ++i; }
    int jj = i + 1 + rem;
    if (kq < 2) { rt = i; ct = jj; } else { rt = jj; ct = i; }
    slice = kq & 1;
    k0 = kq * 1024; klen = 1024;
  } else {
    int dd = (job - 112) >> 1, kh = job & 1;
    rt = ct = dd; slice = kh; k0 = kh * 2048; klen = 2048;
  }
  const int rowTile = rt * 128, colTile = ct * 128;

  __shared__ __align__(16) u16 lAh[128 * 32];
  __shared__ __align__(16) u16 lAl[128 * 32];
  __shared__ __align__(16) u16 lBh[128 * 32];
  __shared__ __align__(16) u16 lBl[128 * 32];
  const int tid  = threadIdx.x;
  const int lane = tid & 63;
  const int wave = tid >> 6;
  const int wr = (wave >> 1) * 64;
  const int wc = (wave & 1) * 64;

  const u16* Ah = XThi + ((size_t)b << 22);
  const u16* Al = XTlo + ((size_t)b << 22);

  f32x4 acc[4][4] = {};
  const int m  = lane & 15;
  const int ko = (lane >> 4) * 8;

  for (int kt = k0; kt < k0 + klen; kt += 32) {
#pragma unroll
    for (int i = 0; i < 2; ++i) {
      int idx = i * 256 + tid;
      int row = idx >> 2;
      int kc  = (idx & 3) * 8;
      int ldsOff = (i * 256 + (tid & 192)) * 16;
      size_t aoff = (size_t)(rowTile + row) * 4096 + kt + kc;
      size_t boff = (size_t)(colTile + row) * 4096 + kt + kc;
      __builtin_amdgcn_global_load_lds(AS1(Ah + aoff), AS3((char*)lAh + ldsOff), 16, 0, 0);
      __builtin_amdgcn_global_load_lds(AS1(Al + aoff), AS3((char*)lAl + ldsOff), 16, 0, 0);
      __builtin_amdgcn_global_load_lds(AS1(Ah + boff), AS3((char*)lBh + ldsOff), 16, 0, 0);
      __builtin_amdgcn_global_load_lds(AS1(Al + boff), AS3((char*)lBl + ldsOff), 16, 0, 0);
    }
    __syncthreads();
    bf16x8 ah[4], al[4], bh[4], bl[4];
#pragma unroll
    for (int rb = 0; rb < 4; ++rb) {
      ah[rb] = *(const bf16x8*)(lAh + (wr + rb * 16 + m) * 32 + ko);
      al[rb] = *(const bf16x8*)(lAl + (wr + rb * 16 + m) * 32 + ko);
    }
#pragma unroll
    for (int cb = 0; cb < 4; ++cb) {
      bh[cb] = *(const bf16x8*)(lBh + (wc + cb * 16 + m) * 32 + ko);
      bl[cb] = *(const bf16x8*)(lBl + (wc + cb * 16 + m) * 32 + ko);
    }
#pragma unroll
    for (int rb = 0; rb < 4; ++rb)
#pragma unroll
      for (int cb = 0; cb < 4; ++cb) {
        acc[rb][cb] = __builtin_amdgcn_mfma_f32_16x16x32_bf16(ah[rb], bh[cb], acc[rb][cb], 0, 0, 0);
        acc[rb][cb] = __builtin_amdgcn_mfma_f32_16x16x32_bf16(ah[rb], bl[cb], acc[rb][cb], 0, 0, 0);
        acc[rb][cb] = __builtin_amdgcn_mfma_f32_16x16x32_bf16(al[rb], bh[cb], acc[rb][cb], 0, 0, 0);
      }
    __syncthreads();
  }

  float* out = Gpart + ((size_t)(slice * 4 + b) << 20);
  const int crow0 = rowTile + wr + (lane >> 4) * 4;
  const int ccol0 = colTile + wc + (lane & 15);
#pragma unroll
  for (int rb = 0; rb < 4; ++rb)
#pragma unroll
    for (int cb = 0; cb < 4; ++cb)
#pragma unroll
      for (int r = 0; r < 4; ++r)
        out[(size_t)(crow0 + rb * 16 + r) * 1024 + ccol0 + cb * 16] = acc[rb][cb][r];
}

// ---------------- tiled reduce: G = S(r,c) [+ S(c,r)^T if off-diag-128] -> bf16 hi/lo ----------------
__global__ __launch_bounds__(256) void gram_reduce_split(const float* __restrict__ Gp,
                                                         u16* __restrict__ Ghi,
                                                         u16* __restrict__ Glo) {
  const int rt = blockIdx.x, ct = blockIdx.y, b = blockIdx.z;  // 64x64 tiles
  const bool diag128 = (rt >> 1) == (ct >> 1);
  const float* s0 = Gp + ((size_t)b << 20);
  const float* s1 = Gp + ((size_t)(4 + b) << 20);
  __shared__ float lT[64 * 68];
  const int t = threadIdx.x;
  const int r = t >> 2;
  const int c16 = (t & 3) * 16;

  if (!diag128) {
    const size_t bb = (size_t)(ct * 64 + r) * 1024 + rt * 64 + c16;
#pragma unroll
    for (int q = 0; q < 4; ++q) {
      float4 v0 = *(const float4*)(s0 + bb + q * 4);
      float4 v1 = *(const float4*)(s1 + bb + q * 4);
      float4 s = { v0.x + v1.x, v0.y + v1.y, v0.z + v1.z, v0.w + v1.w };
      *(float4*)(lT + r * 68 + c16 + q * 4) = s;
    }
    __syncthreads();
  }

  const size_t ab = (size_t)(rt * 64 + r) * 1024 + ct * 64 + c16;
  const size_t ob = ((size_t)b << 20) + ab;
#pragma unroll
  for (int q = 0; q < 4; ++q) {
    float4 v0 = *(const float4*)(s0 + ab + q * 4);
    float4 v1 = *(const float4*)(s1 + ab + q * 4);
    float g[4] = { v0.x + v1.x, v0.y + v1.y, v0.z + v1.z, v0.w + v1.w };
    if (!diag128) {
#pragma unroll
      for (int i = 0; i < 4; ++i) g[i] += lT[(c16 + q * 4 + i) * 68 + r];
    }
    u16x4 oh, ol;
    oh.x = f2bf(g[0]); ol.x = f2bf(g[0] - bf2f(oh.x));
    oh.y = f2bf(g[1]); ol.y = f2bf(g[1] - bf2f(oh.y));
    oh.z = f2bf(g[2]); ol.z = f2bf(g[2] - bf2f(oh.z));
    oh.w = f2bf(g[3]); ol.w = f2bf(g[3] - bf2f(oh.w));
    *(u16x4*)(Ghi + ob + q * 4) = oh;
    *(u16x4*)(Glo + ob + q * 4) = ol;
  }
}

// ---------------- T' = Wq * G^T (G symmetric) per batch, split x3, split-bf16 out ----------------
__global__ __launch_bounds__(256) void gemm_tprime(const u16* __restrict__ Wqh,
                                                   const u16* __restrict__ Wql,
                                                   const u16* __restrict__ Ghi,
                                                   const u16* __restrict__ Glo,
                                                   u16* __restrict__ Tph,
                                                   u16* __restrict__ Tpl) {
  __shared__ __align__(16) u16 lAh[128 * 32];
  __shared__ __align__(16) u16 lAl[128 * 32];
  __shared__ __align__(16) u16 lBh[128 * 32];
  __shared__ __align__(16) u16 lBl[128 * 32];
  const int tid  = threadIdx.x;
  const int lane = tid & 63;
  const int wave = tid >> 6;
  const int rowTile = blockIdx.x * 128;
  const int colTile = blockIdx.y * 128;
  const size_t zoff = (size_t)blockIdx.z << 20;
  const int wr = (wave >> 1) * 64;
  const int wc = (wave & 1) * 64;

  f32x4 acc[4][4] = {};
  const int m  = lane & 15;
  const int ko = (lane >> 4) * 8;

  for (int kt = 0; kt < 1024; kt += 32) {
#pragma unroll
    for (int i = 0; i < 2; ++i) {
      int idx = i * 256 + tid;
      int row = idx >> 2;
      int kc  = (idx & 3) * 8;
      int ldsOff = (i * 256 + (tid & 192)) * 16;
      size_t aoff = (size_t)(rowTile + row) * 1024 + kt + kc;
      size_t boff = zoff + (size_t)(colTile + row) * 1024 + kt + kc;
      __builtin_amdgcn_global_load_lds(AS1(Wqh + aoff), AS3((char*)lAh + ldsOff), 16, 0, 0);
      __builtin_amdgcn_global_load_lds(AS1(Wql + aoff), AS3((char*)lAl + ldsOff), 16, 0, 0);
      __builtin_amdgcn_global_load_lds(AS1(Ghi + boff), AS3((char*)lBh + ldsOff), 16, 0, 0);
      __builtin_amdgcn_global_load_lds(AS1(Glo + boff), AS3((char*)lBl + ldsOff), 16, 0, 0);
    }
    __syncthreads();
    bf16x8 ah[4], al[4], bh[4], bl[4];
#pragma unroll
    for (int rb = 0; rb < 4; ++rb) {
      ah[rb] = *(const bf16x8*)(lAh + (wr + rb * 16 + m) * 32 + ko);
      al[rb] = *(const bf16x8*)(lAl + (wr + rb * 16 + m) * 32 + ko);
    }
#pragma unroll
    for (int cb = 0; cb < 4; ++cb) {
      bh[cb] = *(const bf16x8*)(lBh + (wc + cb * 16 + m) * 32 + ko);
      bl[cb] = *(const bf16x8*)(lBl + (wc + cb * 16 + m) * 32 + ko);
    }
#pragma unroll
    for (int rb = 0; rb < 4; ++rb)
#pragma unroll
      for (int cb = 0; cb < 4; ++cb) {
        acc[rb][cb] = __builtin_amdgcn_mfma_f32_16x16x32_bf16(ah[rb], bh[cb], acc[rb][cb], 0, 0, 0);
        acc[rb][cb] = __builtin_amdgcn_mfma_f32_16x16x32_bf16(ah[rb], bl[cb], acc[rb][cb], 0, 0, 0);
        acc[rb][cb] = __builtin_amdgcn_mfma_f32_16x16x32_bf16(al[rb], bh[cb], acc[rb][cb], 0, 0, 0);
      }
    __syncthreads();
  }

  const int crow0 = rowTile + wr + (lane >> 4) * 4;
  const int ccol0 = colTile + wc + (lane & 15);
#pragma unroll
  for (int rb = 0; rb < 4; ++rb)
#pragma unroll
    for (int cb = 0; cb < 4; ++cb)
#pragma unroll
      for (int r = 0; r < 4; ++r) {
        float v = acc[rb][cb][r];
        u16 hi = f2bf(v);
        u16 lo = f2bf(v - bf2f(hi));
        size_t off = zoff + (size_t)(crow0 + rb * 16 + r) * 1024 + ccol0 + cb * 16;
        Tph[off] = hi;
        Tpl[off] = lo;
      }
}

// ---------------- fused S + softmax ----------------
__global__ __launch_bounds__(256) void s_softmax_kernel(const u16* __restrict__ Wqh,
                                                        const u16* __restrict__ Wql,
                                                        const u16* __restrict__ Tph,
                                                        const u16* __restrict__ Tpl,
                                                        const float* __restrict__ alpha,
                                                        u16* __restrict__ attn) {
  const int h = blockIdx.x, b = blockIdx.y;
  const int tid = threadIdx.x, lane = tid & 63, wave = tid >> 6;
  __shared__ __align__(16) u16 lAh[64 * 32];
  __shared__ __align__(16) u16 lAl[64 * 32];
  __shared__ __align__(16) u16 lBh[64 * 32];
  __shared__ __align__(16) u16 lBl[64 * 32];

  const size_t aBase = (size_t)(1024 + h * 64) * 1024;
  const size_t bBase = ((size_t)b << 20) + (size_t)(h * 64) * 1024;

  f32x4 acc[4] = {};
  const int m  = lane & 15;
  const int ko = (lane >> 4) * 8;
  const int srow = tid >> 2;
  const int skc  = (tid & 3) * 8;
  const int ldsOff = (tid & 192) * 16;

  for (int kt = 0; kt < 1024; kt += 32) {
    __builtin_amdgcn_global_load_lds(AS1(Wqh + aBase + (size_t)srow * 1024 + kt + skc),
                                     AS3((char*)lAh + ldsOff), 16, 0, 0);
    __builtin_amdgcn_global_load_lds(AS1(Wql + aBase + (size_t)srow * 1024 + kt + skc),
                                     AS3((char*)lAl + ldsOff), 16, 0, 0);
    __builtin_amdgcn_global_load_lds(AS1(Tph + bBase + (size_t)srow * 1024 + kt + skc),
                                     AS3((char*)lBh + ldsOff), 16, 0, 0);
    __builtin_amdgcn_global_load_lds(AS1(Tpl + bBase + (size_t)srow * 1024 + kt + skc),
                                     AS3((char*)lBl + ldsOff), 16, 0, 0);
    __syncthreads();
    bf16x8 ah = *(const bf16x8*)(lAh + (wave * 16 + m) * 32 + ko);
    bf16x8 al = *(const bf16x8*)(lAl + (wave * 16 + m) * 32 + ko);
#pragma unroll
    for (int cb = 0; cb < 4; ++cb) {
      bf16x8 bh = *(const bf16x8*)(lBh + (cb * 16 + m) * 32 + ko);
      bf16x8 bl = *(const bf16x8*)(lBl + (cb * 16 + m) * 32 + ko);
      acc[cb] = __builtin_amdgcn_mfma_f32_16x16x32_bf16(ah, bh, acc[cb], 0, 0, 0);
      acc[cb] = __builtin_amdgcn_mfma_f32_16x16x32_bf16(ah, bl, acc[cb], 0, 0, 0);
      acc[cb] = __builtin_amdgcn_mfma_f32_16x16x32_bf16(al, bh, acc[cb], 0, 0, 0);
    }
    __syncthreads();
  }

  const float invA = 1.f / alpha[h];
  const int g = lane >> 4;
  const size_t obase = (size_t)(b * 16 + h) * 4096;
#pragma unroll
  for (int r = 0; r < 4; ++r) {
    int d = wave * 16 + g * 4 + r;
    float s[4];
#pragma unroll
    for (int cb = 0; cb < 4; ++cb) s[cb] = acc[cb][r] * invA;
    float mx = fmaxf(fmaxf(s[0], s[1]), fmaxf(s[2], s[3]));
#pragma unroll
    for (int o = 1; o < 16; o <<= 1) mx = fmaxf(mx, __shfl_xor(mx, o, 64));
    float e[4]; float sum = 0.f;
#pragma unroll
    for (int cb = 0; cb < 4; ++cb) { e[cb] = __expf(s[cb] - mx); sum += e[cb]; }
#pragma unroll
    for (int o = 1; o < 16; o <<= 1) sum += __shfl_xor(sum, o, 64);
    float inv = 1.f / sum;
#pragma unroll
    for (int cb = 0; cb < 4; ++cb)
      attn[obase + (size_t)d * 64 + cb * 16 + (lane & 15)] = f2bf(e[cb] * inv);
  }
}

// ---------------- out_mid = attn @ V^T per (b,h) (MFMA) ----------------
__global__ __launch_bounds__(256) void attnv_kernel(const u16* __restrict__ V,
                                                    const u16* __restrict__ attn,
                                                    u16* __restrict__ outmid) {
  const int tile = blockIdx.x;
  const int h    = blockIdx.y;
  const int tid = threadIdx.x, lane = tid & 63, wave = tid >> 6;
  const int b = (tile * 64) >> 12;
  const int bh = b * 16 + h;
  __shared__ __align__(16) u16 vt[64 * 64];
  __shared__ __align__(16) u16 at[64 * 64];
  const size_t baseV = (size_t)tile * 64 * 1024 + (size_t)h * 64;
#pragma unroll
  for (int i = 0; i < 2; ++i) {
    int idx = i * 256 + tid;
    int tok = idx >> 3;
    int c8  = (idx & 7) * 8;
    int ldsOff = (i * 256 + (tid & 192)) * 16;
    __builtin_amdgcn_global_load_lds(AS1(V + baseV + (size_t)tok * 1024 + c8),
                                     AS3((char*)vt + ldsOff), 16, 0, 0);
    __builtin_amdgcn_global_load_lds(AS1(attn + (size_t)bh * 4096 + idx * 8),
                                     AS3((char*)at + ldsOff), 16, 0, 0);
  }
  __syncthreads();
  const int m  = lane & 15;
  const int ko = (lane >> 4) * 8;
  f32x4 acc[4] = {};
#pragma unroll
  for (int ks = 0; ks < 2; ++ks) {
    bf16x8 a = *(const bf16x8*)(vt + (wave * 16 + m) * 64 + ks * 32 + ko);
#pragma unroll
    for (int cb = 0; cb < 4; ++cb) {
      bf16x8 bb = *(const bf16x8*)(at + (cb * 16 + m) * 64 + ks * 32 + ko);
      acc[cb] = __builtin_amdgcn_mfma_f32_16x16x32_bf16(a, bb, acc[cb], 0, 0, 0);
    }
  }
#pragma unroll
  for (int cb = 0; cb < 4; ++cb) {
    int col = h * 64 + cb * 16 + (lane & 15);
#pragma unroll
    for (int r = 0; r < 4; ++r) {
      int row = tile * 64 + wave * 16 + (lane >> 4) * 4 + r;
      outmid[(size_t)row * 1024 + col] = f2bf(acc[cb][r]);
    }
  }
}

extern "C" void kernel_launch(void* const* d_in, const int* in_sizes, int n_in,
                              void* d_out, int out_size, void* d_ws, size_t ws_size,
                              hipStream_t stream) {
  const float* x     = (const float*)d_in[0];
  const float* Wqkv  = (const float*)d_in[3];
  const float* Wproj = (const float*)d_in[4];
  const float* bproj = (const float*)d_in[5];
  const float* alpha = (const float*)d_in[6];

  char* ws = (char*)d_ws;
  // Region A (33.55 MB): Xb -> Gpart(32 MB) -> outmid
  u16*   Xb     = (u16*)ws;
  float* Gpart  = (float*)ws;
  u16*   outmid = (u16*)ws;
  // Region B (33.55 MB): XThi -> attn
  u16*   XThi  = (u16*)(ws + 33554432);
  u16*   attnb = (u16*)(ws + 33554432);
  // Region C (33.55 MB): XTlo -> {Ghi, Glo, Tph, Tpl}
  u16*   XTlo  = (u16*)(ws + 67108864);
  u16*   Ghi   = (u16*)(ws + 67108864);
  u16*   Glo   = (u16*)(ws + 75497472);
  u16*   Tph   = (u16*)(ws + 83886080);
  u16*   Tpl   = (u16*)(ws + 92274688);
  u16*   Wqh   = (u16*)(ws + 100663296);
  u16*   Wql   = (u16*)(ws + 106954752);
  u16*   Vb    = (u16*)(ws + 113246208);
  u16*   Wpb   = (u16*)(ws + 146800640);   // end: 148.9 MB

  // 1. x -> Xb + XThi/XTlo
  transpose_split_kernel<<<dim3(64, 16, 4), 256, 0, stream>>>(x, Xb, XThi, XTlo);
  // 2. weight converts
  convert_split_kernel<<<256, 256, 0, stream>>>(Wqkv, Wqh, Wql, 3145728 / 4);
  convert_kernel<<<128, 256, 0, stream>>>(Wproj, Wpb, 1048576 / 4);
  // 3. V = X @ Wv^T
  gemm_bt<true, false><<<dim3(128, 8), 256, 0, stream>>>(
      Xb, Wqh + (size_t)2048 * 1024, Vb, nullptr, 16384, 1024, 1024);
  // 4. symmetric Gram partials (overwrites Xb -> after step 3)
  gemm_gram<<<dim3(128, 4), 256, 0, stream>>>(XThi, XTlo, Gpart);
  // 5. tiled transpose-add reduce + hi/lo split (overwrites XTlo region)
  gram_reduce_split<<<dim3(16, 16, 4), 256, 0, stream>>>(Gpart, Ghi, Glo);
  // 6. T' = Wq G
  gemm_tprime<<<dim3(8, 8, 4), 256, 0, stream>>>(Wqh, Wql, Ghi, Glo, Tph, Tpl);
  // 7. fused S + softmax -> attn (overwrites XThi region)
  s_softmax_kernel<<<dim3(16, 4), 256, 0, stream>>>(Wqh, Wql, Tph, Tpl, alpha, attnb);
  // 8. out_mid = attn @ V^T
  attnv_kernel<<<dim3(256, 16), 256, 0, stream>>>(Vb, attnb, outmid);
  // 9. Y = out_mid @ Wproj^T + bproj
  gemm_bt<false, true><<<dim3(128, 8), 256, 0, stream>>>(
      outmid, Wpb, d_out, bproj, 16384, 1024, 1024);
}